// Round 3
// baseline (106.883 us; speedup 1.0000x reference)
//
#include <hip/hip_runtime.h>
#include <hip/hip_bf16.h>

// Problem constants (from reference)
#define BB 4
#define T1 16
#define T2 32
#define TPn 8
#define Hh 16
#define Kk 64
#define Mm 2049   // 2*H*K + 1
// N = 65536

// Output: ct_val [B,T1,T2,M,TP] fp32
// ct_val = (dis_sum[b,t1,t2] - dis_sta[b,t1,t2,tp] + dis_cnc[b,t1,t2,m,tp]) / TP
// distance(c1,c2,v) = sgn(c1)*sgn(c2)*(1 - s)*v, s = table[|c1|^|c2|]
// Reference table: (floor(log2f(x+1)/log2f-const)+1)/16. jnp.log2 = log(x)/log(2)
// in f32: fl(fl(ln(x+1))/fl(ln2)). Exact at x+1=2^k for all k EXCEPT k=13,15
// (k*fl(ln2) not representable; true mantissa 0.474 ulp below the half-integer
// => rounds low => floor = k-1). So:
//   16*(1-s) = __clz(x+1) - 16 + (x==8191) + (x==32767)   [x in 0..65535]

__device__ __forceinline__ float omss16(int x) {
    // 16*(1 - s) per the reference's actual f32 log2 semantics
    int c = __clz(x + 1) - 16;
    if (x == 8191 || x == 32767) c += 1;
    return (float)c;
}

__global__ __launch_bounds__(256)
void critigraph_kernel(const int* __restrict__ sta_loc,   // [B,T1,TP]
                       const int* __restrict__ pos_loc,   // [B,T2,TP]
                       const float* __restrict__ val_n,   // [B,T1,T2]
                       const int* __restrict__ rand_raw,  // [B*T1,H,K,TP]
                       const int* __restrict__ perm,      // [M]
                       float* __restrict__ out)           // [B,T1,T2,M,TP]
{
    const int bt  = blockIdx.x;        // b*T1 + t1
    const int b   = bt / T1;
    const int mc  = blockIdx.y;        // m chunk (0..8)
    const int t2z = blockIdx.z;        // t2 half (0..1), 16 t2 each
    const int tid = threadIdx.x;

    __shared__ int   s_pabs[16 * TPn];   // |pos|
    __shared__ float s_vs8[16 * TPn];    // sgn(pos)*val/8  (signed, per t2,tp)
    __shared__ float s_base8[16 * TPn];  // (dis_sum - dis_sta)/8
    __shared__ float s_dis[16 * TPn];    // dis_sta (temp)
    __shared__ float s_sum[16];          // dis_sum per t2
    __shared__ int   s_ori[TPn];         // |sta|

    if (tid < TPn) {
        int sv = sta_loc[bt * TPn + tid];
        s_ori[tid] = sv < 0 ? -sv : sv;
    }
    if (tid < 16 * TPn) {
        const int t2l = tid >> 3;
        const int tp  = tid & 7;
        const int t2  = t2z * 16 + t2l;
        int pv = pos_loc[(b * T2 + t2) * TPn + tp];
        int pa = pv < 0 ? -pv : pv;
        float psgn = (pv >= 0) ? 1.0f : -1.0f;
        int sv = sta_loc[bt * TPn + tp];
        int sa = sv < 0 ? -sv : sv;
        float ssgn = (sv >= 0) ? 1.0f : -1.0f;
        float v = val_n[bt * T2 + t2];
        int x = sa ^ pa;
        float oms = omss16(x) * 0.0625f;   // 1 - s
        s_dis[tid]  = ssgn * psgn * oms * v;
        s_pabs[tid] = pa;
        s_vs8[tid]  = psgn * v * 0.125f;
    }
    __syncthreads();
    if (tid < 16) {
        const float* d = &s_dis[tid * TPn];
        float acc = 0.0f;
        #pragma unroll
        for (int tp = 0; tp < TPn; ++tp) acc += d[tp];
        s_sum[tid] = acc;
    }
    __syncthreads();
    if (tid < 16 * TPn) {
        s_base8[tid] = (s_sum[tid >> 3] - s_dis[tid]) * 0.125f;
    }
    __syncthreads();

    const int m = mc * 256 + tid;
    if (m >= Mm) return;

    // ---- build candidate coordinate (per tp): magnitude a[tp], sign*0.0625
    int   a[TPn];
    float sg16[TPn];
    const int pm = perm[m];
    if (pm == Hh * Kk) {   // == 1024: the original coordinate
        #pragma unroll
        for (int tp = 0; tp < TPn; ++tp) { a[tp] = s_ori[tp]; sg16[tp] = 0.0625f; }
    } else {
        const int r   = (pm < Hh * Kk) ? pm : pm - (Hh * Kk + 1);
        const float ng = (pm < Hh * Kk) ? 0.0625f : -0.0625f;
        const int j   = r >> 6;           // r / K
        const int k   = r & 63;           // r % K
        const int mb  = (1 << j) - 1;     // mod 2^j
        const int flip = 1 << j;
        const int* rr = rand_raw + ((bt * Hh + j) * Kk + k) * TPn;
        #pragma unroll
        for (int tp = 0; tp < TPn; ++tp) {
            int res = (s_ori[tp] ^ flip) ^ (rr[tp] & mb);
            a[tp] = res;
            sg16[tp] = (res == 0) ? 0.0625f : ng;  // sign(+0)=+1
        }
    }

    // ---- main loop over 16 t2 values; 8 outputs (32B) per step
    float* op = out + ((long long)(bt * T2 + t2z * 16) * Mm + m) * TPn;
    #pragma unroll 4
    for (int t2l = 0; t2l < 16; ++t2l) {
        float o[TPn];
        #pragma unroll
        for (int tp = 0; tp < TPn; ++tp) {
            const int idx = t2l * TPn + tp;
            int x = a[tp] ^ s_pabs[idx];
            float c = omss16(x);                    // 16*(1-s)
            o[tp] = fmaf(c * sg16[tp], s_vs8[idx], s_base8[idx]);
        }
        float4* q = (float4*)(op + (long long)t2l * (Mm * TPn));
        q[0] = make_float4(o[0], o[1], o[2], o[3]);
        q[1] = make_float4(o[4], o[5], o[6], o[7]);
    }
}

extern "C" void kernel_launch(void* const* d_in, const int* in_sizes, int n_in,
                              void* d_out, int out_size, void* d_ws, size_t ws_size,
                              hipStream_t stream) {
    const int*   sta_loc  = (const int*)d_in[0];
    const int*   pos_loc  = (const int*)d_in[1];
    const float* val_n    = (const float*)d_in[2];
    const int*   rand_raw = (const int*)d_in[3];
    const int*   perm     = (const int*)d_in[4];
    float* out = (float*)d_out;

    dim3 grid(BB * T1, (Mm + 255) / 256, 2);   // (64, 9, 2)
    critigraph_kernel<<<grid, 256, 0, stream>>>(sta_loc, pos_loc, val_n,
                                                rand_raw, perm, out);
}

// Round 4
// 30.190 us; speedup vs baseline: 3.5403x; 3.5403x over previous
//
#include <hip/hip_runtime.h>
#include <hip/hip_bf16.h>

// Problem constants (from reference)
#define BB 4
#define T1 16
#define T2 32
#define TPn 8
#define Hh 16
#define Kk 64
#define Mm 2049   // 2*H*K + 1
#define NT2B 8    // t2 values handled per block (T2/4)

// Output: ct_val [B,T1,T2,M,TP] fp32
// ct_val = (dis_sum[b,t1,t2] - dis_sta[b,t1,t2,tp] + dis_cnc[b,t1,t2,m,tp]) / TP
// distance(c1,c2,v) = sgn(c1)*sgn(c2)*(1 - s)*v, s = table[|c1|^|c2|]
// Reference table semantics (verified R3, absmax 3.7e-9): f32 log(x)/log(2) is
// exact at x+1=2^k for all k except k=13,15 (rounds one ulp low => floor=k-1):
//   16*(1-s) = __clz(x+1) - 16 + (x==8191) + (x==32767)

__device__ __forceinline__ float omss16(int x) {
    int c = __clz(x + 1) - 16;
    if (x == 8191 || x == 32767) c += 1;
    return (float)c;
}

__global__ __launch_bounds__(256)
void critigraph_kernel(const int* __restrict__ sta_loc,   // [B,T1,TP]
                       const int* __restrict__ pos_loc,   // [B,T2,TP]
                       const float* __restrict__ val_n,   // [B,T1,T2]
                       const int* __restrict__ rand_raw,  // [B*T1,H,K,TP]
                       const int* __restrict__ perm,      // [M]
                       float* __restrict__ out)           // [B,T1,T2,M,TP]
{
    const int bt  = blockIdx.x;        // b*T1 + t1
    const int b   = bt / T1;
    const int mc  = blockIdx.y;        // m chunk of 128 (0..16)
    const int t2q = blockIdx.z;        // t2 quarter (0..3), 8 t2 each
    const int tid = threadIdx.x;

    __shared__ __align__(16) int   s_pabs[NT2B * TPn];   // |pos|
    __shared__ __align__(16) float s_vs8[NT2B * TPn];    // sgn(pos)*val/8
    __shared__ __align__(16) float s_base8[NT2B * TPn];  // (dis_sum - dis_sta)/8
    __shared__ float s_dis[NT2B * TPn];                  // dis_sta (temp)
    __shared__ float s_sum[NT2B];                        // dis_sum per t2
    __shared__ int   s_ori[TPn];                         // |sta|

    if (tid < TPn) {
        int sv = sta_loc[bt * TPn + tid];
        s_ori[tid] = sv < 0 ? -sv : sv;
    }
    if (tid < NT2B * TPn) {
        const int t2l = tid >> 3;
        const int tp  = tid & 7;
        const int t2  = t2q * NT2B + t2l;
        int pv = pos_loc[(b * T2 + t2) * TPn + tp];
        int pa = pv < 0 ? -pv : pv;
        float psgn = (pv >= 0) ? 1.0f : -1.0f;
        int sv = sta_loc[bt * TPn + tp];
        int sa = sv < 0 ? -sv : sv;
        float ssgn = (sv >= 0) ? 1.0f : -1.0f;
        float v = val_n[bt * T2 + t2];
        int x = sa ^ pa;
        s_dis[tid]  = ssgn * psgn * (omss16(x) * 0.0625f) * v;
        s_pabs[tid] = pa;
        s_vs8[tid]  = psgn * v * 0.125f;
    }
    __syncthreads();
    if (tid < NT2B) {
        const float* d = &s_dis[tid * TPn];
        float acc = 0.0f;
        #pragma unroll
        for (int tp = 0; tp < TPn; ++tp) acc += d[tp];
        s_sum[tid] = acc;
    }
    __syncthreads();
    if (tid < NT2B * TPn) {
        s_base8[tid] = (s_sum[tid >> 3] - s_dis[tid]) * 0.125f;
    }
    __syncthreads();

    const int m = mc * 128 + (tid >> 1);
    if (m >= Mm) return;
    const int q4 = (tid & 1) * 4;          // which half of the 8 tp's

    // ---- build candidate coordinate for tp in [q4, q4+4)
    int   a[4];
    float sg16[4];
    const int pm = perm[m];
    if (pm == Hh * Kk) {   // == 1024: the original coordinate
        #pragma unroll
        for (int j = 0; j < 4; ++j) { a[j] = s_ori[q4 + j]; sg16[j] = 0.0625f; }
    } else {
        const int r   = (pm < Hh * Kk) ? pm : pm - (Hh * Kk + 1);
        const float ng = (pm < Hh * Kk) ? 0.0625f : -0.0625f;
        const int jj  = r >> 6;           // r / K
        const int k   = r & 63;           // r % K
        const int mb  = (1 << jj) - 1;    // mod 2^jj
        const int flip = 1 << jj;
        const int* rr = rand_raw + ((bt * Hh + jj) * Kk + k) * TPn + q4;
        #pragma unroll
        for (int j = 0; j < 4; ++j) {
            int res = (s_ori[q4 + j] ^ flip) ^ (rr[j] & mb);
            a[j] = res;
            sg16[j] = (res == 0) ? 0.0625f : ng;  // sign(+0)=+1
        }
    }

    // ---- 8 t2 iterations; one fully-coalesced float4 store each
    // lane tid writes bytes [tid*16, tid*16+16) of each wave's 1KB span
    float* op = out + ((long long)(bt * T2 + t2q * NT2B) * Mm + m) * TPn + q4;
    #pragma unroll
    for (int t2l = 0; t2l < NT2B; ++t2l) {
        const int idx = t2l * TPn + q4;
        const float4 vs = *(const float4*)&s_vs8[idx];
        const float4 bs = *(const float4*)&s_base8[idx];
        float4 o;
        o.x = fmaf(omss16(a[0] ^ s_pabs[idx + 0]) * sg16[0], vs.x, bs.x);
        o.y = fmaf(omss16(a[1] ^ s_pabs[idx + 1]) * sg16[1], vs.y, bs.y);
        o.z = fmaf(omss16(a[2] ^ s_pabs[idx + 2]) * sg16[2], vs.z, bs.z);
        o.w = fmaf(omss16(a[3] ^ s_pabs[idx + 3]) * sg16[3], vs.w, bs.w);
        *(float4*)(op + (long long)t2l * (Mm * TPn)) = o;
    }
}

extern "C" void kernel_launch(void* const* d_in, const int* in_sizes, int n_in,
                              void* d_out, int out_size, void* d_ws, size_t ws_size,
                              hipStream_t stream) {
    const int*   sta_loc  = (const int*)d_in[0];
    const int*   pos_loc  = (const int*)d_in[1];
    const float* val_n    = (const float*)d_in[2];
    const int*   rand_raw = (const int*)d_in[3];
    const int*   perm     = (const int*)d_in[4];
    float* out = (float*)d_out;

    dim3 grid(BB * T1, (Mm + 127) / 128, 4);   // (64, 17, 4) = 4352 blocks
    critigraph_kernel<<<grid, 256, 0, stream>>>(sta_loc, pos_loc, val_n,
                                                rand_raw, perm, out);
}